// Round 5
// baseline (276.063 us; speedup 1.0000x reference)
//
#include <hip/hip_runtime.h>
#include <hip/hip_bf16.h>
#include <math.h>

// Problem constants (fixed by the reference)
#define NSEG 32
#define T_DIM 8
#define F_DIM 32
#define P_DIM 8
#define OUT_PER_SEG 2048 // T*P*F
#define EPS_DENOM 1e-16f
#define CHUNK 128        // nodes per accum block
#define MAXBLK 1024      // max accum blocks (N=100000 -> 782)

// Tiny MLP: h = elu(pos @ W1 + b1) @ W2 + b2  (per node, P=8 outputs)
__device__ __forceinline__ void compute_h(
    float h[P_DIM], const float* __restrict__ pos, int n,
    const float* __restrict__ W1, const float* __restrict__ b1,
    const float* __restrict__ W2, const float* __restrict__ b2) {
  float p0 = pos[3 * n + 0];
  float p1 = pos[3 * n + 1];
  float p2 = pos[3 * n + 2];
  float a[P_DIM];
#pragma unroll
  for (int p = 0; p < P_DIM; p++) {
    float v = b1[p] + p0 * W1[0 * P_DIM + p] + p1 * W1[1 * P_DIM + p] + p2 * W1[2 * P_DIM + p];
    a[p] = v > 0.f ? v : (__expf(v) - 1.f);  // ELU alpha=1
  }
#pragma unroll
  for (int p = 0; p < P_DIM; p++) {
    float v = b2[p];
#pragma unroll
    for (int j = 0; j < P_DIM; j++) v += a[j] * W2[j * P_DIM + p];
    h[p] = v;
  }
}

// Kernel 1: per-segment sum of exp(h) (no max shift: |h| small, fp32-safe,
// verified R3/R4 absmax 4.9e-4 vs 1.16e-2 threshold). Wave pre-reduction.
__global__ __launch_bounds__(256) void sum_kernel(
    const float* __restrict__ pos, const int* __restrict__ seg,
    const float* __restrict__ W1, const float* __restrict__ b1,
    const float* __restrict__ W2, const float* __restrict__ b2,
    float* __restrict__ sSum, int N) {
  int tid = threadIdx.x;
  int n = blockIdx.x * 256 + tid;
  bool valid = n < N;
  int nn = valid ? n : N - 1;
  int sg = seg[nn];
  float h[P_DIM];
  compute_h(h, pos, nn, W1, b1, W2, b2);
  float e[P_DIM];
#pragma unroll
  for (int p = 0; p < P_DIM; p++) e[p] = valid ? __expf(h[p]) : 0.f;
  int sg0 = __shfl(sg, 0, 64);
  if (__all(sg == sg0)) {
#pragma unroll
    for (int off = 32; off >= 1; off >>= 1)
#pragma unroll
      for (int p = 0; p < P_DIM; p++) e[p] += __shfl_down(e[p], off, 64);
    if ((tid & 63) == 0) {
#pragma unroll
      for (int p = 0; p < P_DIM; p++) unsafeAtomicAdd(&sSum[sg * 8 + p], e[p]);
    }
  } else if (valid) {
#pragma unroll
    for (int p = 0; p < P_DIM; p++) unsafeAtomicAdd(&sSum[sg * 8 + p], e[p]);
  }
}

// 32 atomic f32 adds for one wave-lane (slow path only; RAW-e partials)
__device__ __forceinline__ void flush32(float* __restrict__ out, int sg, int t,
                                        int f4, float4 acc4[P_DIM]) {
  float* bo = out + sg * OUT_PER_SEG + t * (P_DIM * F_DIM) + f4 * 4;
#pragma unroll
  for (int p = 0; p < P_DIM; p++) {
    unsafeAtomicAdd(bo + p * F_DIM + 0, acc4[p].x);
    unsafeAtomicAdd(bo + p * F_DIM + 1, acc4[p].y);
    unsafeAtomicAdd(bo + p * F_DIM + 2, acc4[p].z);
    unsafeAtomicAdd(bo + p * F_DIM + 3, acc4[p].w);
    acc4[p] = make_float4(0.f, 0.f, 0.f, 0.f);
  }
}

#define FMA_NODE(XV, WA, WB)                                                   \
  do {                                                                         \
    acc4[0].x += (XV).x * (WA).x; acc4[0].y += (XV).y * (WA).x;                \
    acc4[0].z += (XV).z * (WA).x; acc4[0].w += (XV).w * (WA).x;                \
    acc4[1].x += (XV).x * (WA).y; acc4[1].y += (XV).y * (WA).y;                \
    acc4[1].z += (XV).z * (WA).y; acc4[1].w += (XV).w * (WA).y;                \
    acc4[2].x += (XV).x * (WA).z; acc4[2].y += (XV).y * (WA).z;                \
    acc4[2].z += (XV).z * (WA).z; acc4[2].w += (XV).w * (WA).z;                \
    acc4[3].x += (XV).x * (WA).w; acc4[3].y += (XV).y * (WA).w;                \
    acc4[3].z += (XV).z * (WA).w; acc4[3].w += (XV).w * (WA).w;                \
    acc4[4].x += (XV).x * (WB).x; acc4[4].y += (XV).y * (WB).x;                \
    acc4[4].z += (XV).z * (WB).x; acc4[4].w += (XV).w * (WB).x;                \
    acc4[5].x += (XV).x * (WB).y; acc4[5].y += (XV).y * (WB).y;                \
    acc4[5].z += (XV).z * (WB).y; acc4[5].w += (XV).w * (WB).y;                \
    acc4[6].x += (XV).x * (WB).z; acc4[6].y += (XV).y * (WB).z;                \
    acc4[6].z += (XV).z * (WB).z; acc4[6].w += (XV).w * (WB).z;                \
    acc4[7].x += (XV).x * (WB).w; acc4[7].y += (XV).y * (WB).w;                \
    acc4[7].z += (XV).z * (WB).w; acc4[7].w += (XV).w * (WB).w;                \
  } while (0)

#define CONSUME(BUF, OFF)                                                      \
  do {                                                                         \
    _Pragma("unroll")                                                          \
    for (int j = 0; j < 8; j++) {                                              \
      int nd = w + 4 * ((OFF) + j);                                            \
      float4 wa = *(const float4*)&wbuf[nd][0];                                \
      float4 wb = *(const float4*)&wbuf[nd][4];                                \
      FMA_NODE(BUF[j], wa, wb);                                                \
    }                                                                          \
  } while (0)

// Kernel 2: heavy accumulation with NO output atomics on the fast path.
// (R1/R3/R4 all plateaued at ~87us regardless of load structure: the wall was
// 1.6M device atomics bouncing 1024 lines across 8 XCDs, 36 B HBM
// writeback/atomic. Softmax denom factors out per (seg,p), so we accumulate
// RAW e-weighted sums and normalize in the reduce kernel.)
// Block = 256 thr owns CHUNK=128 nodes. Phase A: inline MLP -> e -> wbuf (no
// e8 round-trip). Phase B: float4-stream x, 8-deep groups. Flush: cross-wave
// LDS reduce -> plain float4 stores to private partial[blk] slot.
__global__ __launch_bounds__(256, 4) void accum_kernel(
    const float* __restrict__ x, const float* __restrict__ pos,
    const int* __restrict__ seg,
    const float* __restrict__ W1, const float* __restrict__ b1,
    const float* __restrict__ W2, const float* __restrict__ b2,
    float* __restrict__ partial, int* __restrict__ blkseg,
    float* __restrict__ out, int N) {
  __shared__ __align__(16) float wbuf[CHUNK][P_DIM];     // 4 KB
  __shared__ int sbuf[CHUNK];                            // 512 B
  __shared__ __align__(16) float redbuf[4][OUT_PER_SEG]; // 32 KB, output order

  int tid = threadIdx.x;
  int base = blockIdx.x * CHUNK;
  int cnt = N - base;
  if (cnt > CHUNK) cnt = CHUNK;

  if (tid < cnt) {
    int n = base + tid;
    sbuf[tid] = seg[n];
    float h[P_DIM];
    compute_h(h, pos, n, W1, b1, W2, b2);
#pragma unroll
    for (int p = 0; p < P_DIM; p++) wbuf[tid][p] = __expf(h[p]);  // RAW e
  }
  __syncthreads();

  int w = tid >> 6, lane = tid & 63;
  int t = lane >> 3, f4 = lane & 7;
  const float4* xq = (const float4*)x + (size_t)base * 64 + lane;

  float4 acc4[P_DIM];
#pragma unroll
  for (int p = 0; p < P_DIM; p++) acc4[p] = make_float4(0.f, 0.f, 0.f, 0.f);

  bool fast = (cnt == CHUNK) && (sbuf[0] == sbuf[CHUNK - 1]);

  if (fast) {
    float4 xa[8], xb[8];
#pragma unroll
    for (int j = 0; j < 8; j++) xa[j] = xq[(size_t)(w + 4 * j) * 64];
#pragma unroll
    for (int j = 0; j < 8; j++) xb[j] = xq[(size_t)(w + 4 * (8 + j)) * 64];
    CONSUME(xa, 0);
#pragma unroll
    for (int j = 0; j < 8; j++) xa[j] = xq[(size_t)(w + 4 * (16 + j)) * 64];
    CONSUME(xb, 8);
#pragma unroll
    for (int j = 0; j < 8; j++) xb[j] = xq[(size_t)(w + 4 * (24 + j)) * 64];
    CONSUME(xa, 16);
    CONSUME(xb, 24);

    // stage this wave's partials in output-flat order
    float* rb = &redbuf[w][t * (P_DIM * F_DIM) + f4 * 4];
#pragma unroll
    for (int p = 0; p < P_DIM; p++) *(float4*)(rb + p * F_DIM) = acc4[p];
    __syncthreads();

    // block flush: thread owns 8 contiguous words -> PLAIN stores to own slot
    float* po = partial + (size_t)blockIdx.x * OUT_PER_SEG + 8 * tid;
#pragma unroll
    for (int half = 0; half < 2; half++) {
      float4 v0 = *(const float4*)&redbuf[0][8 * tid + 4 * half];
      float4 v1 = *(const float4*)&redbuf[1][8 * tid + 4 * half];
      float4 v2 = *(const float4*)&redbuf[2][8 * tid + 4 * half];
      float4 v3 = *(const float4*)&redbuf[3][8 * tid + 4 * half];
      float4 s;
      s.x = v0.x + v1.x + v2.x + v3.x;
      s.y = v0.y + v1.y + v2.y + v3.y;
      s.z = v0.z + v1.z + v2.z + v3.z;
      s.w = v0.w + v1.w + v2.w + v3.w;
      *(float4*)(po + 4 * half) = s;
    }
    if (tid == 0) blkseg[blockIdx.x] = sbuf[0];
  } else {
    // boundary/tail blocks (rare): RAW-e atomics to out, slot marked unused
    if (tid == 0) blkseg[blockIdx.x] = -1;
    if (w < cnt) {
      int cur = sbuf[w];
      for (int nd = w; nd < cnt; nd += 4) {
        int sgi = sbuf[nd];
        if (sgi != cur) {
          flush32(out, cur, t, f4, acc4);
          cur = sgi;
        }
        float4 xv = xq[(size_t)nd * 64];
        float4 wa = *(const float4*)&wbuf[nd][0];
        float4 wb = *(const float4*)&wbuf[nd][4];
        FMA_NODE(xv, wa, wb);
      }
      flush32(out, cur, t, f4, acc4);
    }
  }
}

// Kernel 3: final reduction + normalization. Grid = 32 segs x 8 j-chunks.
// out[s][j] = (out[s][j](slow residue) + sum of matching partial slots) / (S+eps)
__global__ __launch_bounds__(256) void reduce_kernel(
    const float* __restrict__ partial, const int* __restrict__ blkseg,
    const float* __restrict__ sSum, float* __restrict__ out, int nblk) {
  __shared__ int sblk[MAXBLK];
  int s = blockIdx.x >> 3;
  int jbase = (blockIdx.x & 7) * 256;
  int tid = threadIdx.x;
  for (int i = tid; i < nblk; i += 256) sblk[i] = blkseg[i];
  __syncthreads();
  int j = jbase + tid;
  float v = 0.f;
  for (int b = 0; b < nblk; b++) {
    if (sblk[b] == s) v += partial[(size_t)b * OUT_PER_SEG + j];
  }
  int p = (j >> 5) & 7;
  float inv = 1.f / (sSum[s * 8 + p] + EPS_DENOM);
  int oj = s * OUT_PER_SEG + j;
  out[oj] = (out[oj] + v) * inv;
}

extern "C" void kernel_launch(void* const* d_in, const int* in_sizes, int n_in,
                              void* d_out, int out_size, void* d_ws, size_t ws_size,
                              hipStream_t stream) {
  const float* pos = (const float*)d_in[0];
  const float* x   = (const float*)d_in[1];
  const int*   seg = (const int*)d_in[2];
  const float* W1  = (const float*)d_in[3];
  const float* b1  = (const float*)d_in[4];
  const float* W2  = (const float*)d_in[5];
  const float* b2  = (const float*)d_in[6];
  float* out = (float*)d_out;
  int N = in_sizes[2];
  int nblk = (N + CHUNK - 1) / CHUNK;

  // ws layout: sSum [256 f, 1 KB] | blkseg [1024 int, 4 KB] | partial [nblk][2048] f
  float* sSum    = (float*)d_ws;
  int*   blkseg  = (int*)((char*)d_ws + 1024);
  float* partial = (float*)((char*)d_ws + 1024 + MAXBLK * sizeof(int));

  hipMemsetAsync(d_out, 0, (size_t)out_size * sizeof(float), stream);
  hipMemsetAsync(d_ws, 0, NSEG * 8 * sizeof(float), stream);

  int nb = (N + 255) / 256;
  sum_kernel<<<nb, 256, 0, stream>>>(pos, seg, W1, b1, W2, b2, sSum, N);

  accum_kernel<<<nblk, 256, 0, stream>>>(x, pos, seg, W1, b1, W2, b2,
                                         partial, blkseg, out, N);

  reduce_kernel<<<NSEG * 8, 256, 0, stream>>>(partial, blkseg, sSum, out, nblk);
}